// Round 9
// baseline (502.768 us; speedup 1.0000x reference)
//
#include <hip/hip_runtime.h>

#define SEQ 2048
#define NB 4
#define DIN 768
#define EDIM 768
#define NH 12
#define QKVN 2304
#define QKW 1536
#define SCALE 0.125f
#define PADV -1e9f
#define INV12 (0.0833333333f)
#define ACCW 523   // accs row stride (odd*? -> ~2-way LDS banks on atomics)

typedef unsigned short ushort_t;
typedef __attribute__((ext_vector_type(8))) short bf16x8;
typedef __attribute__((ext_vector_type(4))) float f32x4;

__device__ __forceinline__ float bf2f(ushort_t u) {
    union { unsigned int i; float f; } v; v.i = ((unsigned int)u) << 16; return v.f;
}
__device__ __forceinline__ ushort_t f2bf(float f) {
    union { float f; unsigned int i; } v; v.f = f;
    unsigned int r = (v.i + 0x7fffu + ((v.i >> 16) & 1u)) >> 16;
    return (ushort_t)r;
}
__device__ __forceinline__ unsigned int pack2bf(float a, float b) {
    return (unsigned int)f2bf(a) | ((unsigned int)f2bf(b) << 16);
}
__device__ __forceinline__ void gl_lds16(const ushort_t* g, ushort_t* l) {
    __builtin_amdgcn_global_load_lds(
        (const __attribute__((address_space(1))) unsigned int*)(g),
        (__attribute__((address_space(3))) unsigned int*)(l),
        16, 0, 0);
}

// ---------------- per-batch window size ----------------
__global__ void wsz_kernel(const int* __restrict__ mask, int* __restrict__ wszp) {
    int b = blockIdx.x;
    __shared__ int cnt;
    if (threadIdx.x == 0) cnt = 0;
    __syncthreads();
    int local = 0;
    for (int s = threadIdx.x; s < SEQ; s += blockDim.x)
        local += (mask[b * SEQ + s] == 0) ? 1 : 0;
    for (int o = 32; o; o >>= 1) local += __shfl_down(local, o, 64);
    if ((threadIdx.x & 63) == 0) atomicAdd(&cnt, local);
    __syncthreads();
    if (threadIdx.x == 0) {
        int len = cnt; if (len > 2048) len = 2048;
        float w = ceilf(((float)len * 10.0f) / 100.0f);
        int wsz = (int)w;
        if (wsz < 2) wsz = 2;
        wszp[b] = wsz;
    }
}

// ---------------- fp32 -> bf16 conversion, 3 regions in one launch ----------------
__global__ void cvt3_kernel(const float* __restrict__ s0, int n0,
                            const float* __restrict__ s1, int n1,
                            const float* __restrict__ s2, int n2,
                            ushort_t* __restrict__ d0, ushort_t* __restrict__ d1,
                            ushort_t* __restrict__ d2) {
    int i = blockIdx.x * blockDim.x + threadIdx.x;
    const float* src; ushort_t* dst; int off;
    if (i < n0)               { src = s0; dst = d0; off = i; }
    else if (i < n0 + n1)     { src = s1; dst = d1; off = i - n0; }
    else if (i < n0 + n1 + n2){ src = s2; dst = d2; off = i - n0 - n1; }
    else return;
    float4 f = ((const float4*)src)[off];
    ushort4 u;
    u.x = f2bf(f.x); u.y = f2bf(f.y); u.z = f2bf(f.z); u.w = f2bf(f.w);
    ((ushort4*)dst)[off] = u;
}

// ---------------- mmask nonzero-tile flags ----------------
__global__ void flag_kernel(const float* __restrict__ mmask, const int* __restrict__ wszp,
                            int* __restrict__ flags) {
    const int b = blockIdx.z, i16 = blockIdx.y;
    const int wsz = wszp[b];
    const int i0 = i16 * 16;
    const int jt0 = max(0, i0 - wsz) >> 6;
    const int jt1 = min(SEQ - 1, i0 + 15 + wsz) >> 6;
    const int jt = jt0 + blockIdx.x;
    if (jt > jt1) return;
    int any = 0;
    for (int e = threadIdx.x; e < 1024; e += 256) {
        int row = e >> 6, col = e & 63;
        float v = mmask[((size_t)b * SEQ + i0 + row) * SEQ + jt * 64 + col];
        any |= (v != 0.f);
    }
    if (any) flags[(b * 128 + i16) * 32 + jt] = 1;
}

// ---------------- 128x128 bf16 MFMA GEMM ----------------
template<int MODE>
__global__ __launch_bounds__(256) void mfma_gemm128(
    const ushort_t* __restrict__ A, const ushort_t* __restrict__ Bw,
    const float* __restrict__ bias, float* __restrict__ outf,
    ushort_t* __restrict__ qk, ushort_t* __restrict__ vt, int N, int K)
{
    __shared__ __align__(16) ushort_t Al[128 * 64];
    __shared__ __align__(16) ushort_t Bl[128 * 64];
    const int tid  = threadIdx.x;
    const int w    = tid >> 6;
    const int l    = tid & 63;
    const int quad = l >> 4;
    const int lr   = l & 15;
    const int mw   = (w >> 1) * 64;
    const int nw   = (w & 1) * 64;
    const int bm   = blockIdx.y * 128;
    const int bn   = blockIdx.x * 128;
    const int srow = l >> 3;
    const int sg   = (l & 7) ^ srow;

    f32x4 acc[4][4];
    #pragma unroll
    for (int i = 0; i < 4; ++i)
        #pragma unroll
        for (int j = 0; j < 4; ++j)
            #pragma unroll
            for (int r = 0; r < 4; ++r) acc[i][j][r] = 0.f;

    const ushort_t* ga = A  + (size_t)(bm + w * 32 + srow) * K + sg * 8;
    const ushort_t* gb = Bw + (size_t)(bn + w * 32 + srow) * K + sg * 8;
    ushort_t* la = &Al[(w * 32) * 64];
    ushort_t* lb = &Bl[(w * 32) * 64];

    for (int k0 = 0; k0 < K; k0 += 64) {
        __syncthreads();
        #pragma unroll
        for (int i = 0; i < 4; ++i)
            gl_lds16(ga + (size_t)(i * 8) * K + k0, la + i * 8 * 64);
        #pragma unroll
        for (int i = 0; i < 4; ++i)
            gl_lds16(gb + (size_t)(i * 8) * K + k0, lb + i * 8 * 64);
        __syncthreads();
        #pragma unroll
        for (int s = 0; s < 2; ++s) {
            bf16x8 af[4], bf[4];
            #pragma unroll
            for (int t = 0; t < 4; ++t)
                af[t] = *(const bf16x8*)&Al[(mw + t * 16 + lr) * 64 + (((4 * s + quad) ^ (lr & 7)) * 8)];
            #pragma unroll
            for (int t = 0; t < 4; ++t)
                bf[t] = *(const bf16x8*)&Bl[(nw + t * 16 + lr) * 64 + (((4 * s + quad) ^ (lr & 7)) * 8)];
            #pragma unroll
            for (int mt = 0; mt < 4; ++mt)
                #pragma unroll
                for (int nt = 0; nt < 4; ++nt)
                    acc[mt][nt] = __builtin_amdgcn_mfma_f32_16x16x32_bf16(af[mt], bf[nt], acc[mt][nt], 0, 0, 0);
        }
    }

    #pragma unroll
    for (int nt = 0; nt < 4; ++nt) {
        const int gn = bn + nw + nt * 16 + lr;
        const float bv = bias[gn];
        const int hh  = gn / 192;
        const int rem = gn - hh * 192;
        #pragma unroll
        for (int mt = 0; mt < 4; ++mt) {
            const int gm0 = bm + mw + mt * 16 + quad * 4;
            if (MODE == 0) {
                #pragma unroll
                for (int r = 0; r < 4; ++r)
                    outf[(size_t)(gm0 + r) * N + gn] = acc[mt][nt][r] + bv;
            } else if (rem < 128) {
                #pragma unroll
                for (int r = 0; r < 4; ++r)
                    qk[(size_t)(gm0 + r) * QKW + hh * 128 + rem] = f2bf(acc[mt][nt][r] + bv);
            } else {
                const int bb  = gm0 >> 11;
                const int tok = gm0 & (SEQ - 1);
                ushort4 st;
                st.x = f2bf(acc[mt][nt][0] + bv);
                st.y = f2bf(acc[mt][nt][1] + bv);
                st.z = f2bf(acc[mt][nt][2] + bv);
                st.w = f2bf(acc[mt][nt][3] + bv);
                *(ushort4*)&vt[((size_t)(bb * NH + hh) * 64 + (rem - 128)) * SEQ + tok] = st;
            }
        }
    }
}

// ---------------- fused windowed attention v7: barrier-free, 1 wave = 1 head ----------
// Grid 512 (XCD-swizzled), 768 thr = 12 waves = 12 heads. S computed TRANSPOSED
// (A=K, B=Q -> D col = q-row, row = token), so lsum is an in-wave shuffle, the
// head-mean goes through LDS atomics (accs), and P round-trips a tiny per-wave
// LDS slab to become PV A-fragments. Only 2 block barriers (init / readout).
__global__ __launch_bounds__(768, 6) void attn_kernel(
    const ushort_t* __restrict__ qk,    // [NB*SEQ][1536] bf16 (Q|K per head)
    const ushort_t* __restrict__ vt,    // [NB*NH*64][SEQ] bf16 (V transposed)
    const float* __restrict__ mmask,    // [NB][SEQ][SEQ]
    const int* __restrict__ wszp,       // [NB]
    const int* __restrict__ flags,      // [NB][128][32]
    ushort_t* __restrict__ values,      // [NB*SEQ][768] bf16
    float* __restrict__ attn_out)       // [NB][SEQ][SEQ]
{
    __shared__ float accs[16 * ACCW];                     // 33.5 KB head-mean accum
    __shared__ __align__(16) ushort_t Pbuf[12 * 16 * 72]; // 27.6 KB per-wave P slabs
    const int tid  = threadIdx.x;
    const int w    = tid >> 6;       // wave = head
    const int lane = tid & 63;
    const int quad = lane >> 4;
    const int l15  = lane & 15;

    const int lin  = blockIdx.x;
    const int s    = lin & 1;
    const int b    = (lin >> 1) & 3;
    const int i16  = (lin >> 3) + 64 * s;
    const int iq0  = i16 * 16;

    const int wsz  = wszp[b];
    const int jlo  = max(0, iq0 - wsz);
    const int jhi  = min(SEQ - 1, iq0 + 15 + wsz);
    const int jt0  = jlo >> 6;
    const int nch  = (jhi >> 6) - jt0 + 1;   // <= 8
    const int jbase = jt0 << 6;
    const int span  = nch << 6;              // <= 512
    const int fbase = (b * 128 + i16) * 32;

    // zero head-mean accumulator
    for (int i = tid; i < 16 * ACCW; i += 768) accs[i] = 0.f;
    __syncthreads();

    const int h = w;
    const ushort_t* qbase = qk + (size_t)(b * SEQ + iq0 + l15) * QKW + h * 128;
    const bf16x8 qf0 = *(const bf16x8*)(qbase + quad * 8);
    const bf16x8 qf1 = *(const bf16x8*)(qbase + 32 + quad * 8);
    const ushort_t* kbase = qk + (size_t)b * SEQ * QKW + h * 128 + 64;
    const ushort_t* vbase = vt + (size_t)((b * NH + h) * 64) * SEQ;

    const int gi = iq0 + l15;                    // this lane's q-row (S^T col)
    const float* mrow = mmask + ((size_t)b * SEQ + gi) * SEQ;

    // ---- pass A: row sums only ----
    float lsum = 0.f;
    for (int ci = 0; ci < nch; ++ci) {
        const int jc = jbase + ci * 64;
        const int anym = flags[fbase + jt0 + ci];
        #pragma unroll
        for (int t = 0; t < 4; ++t) {
            const ushort_t* kr = kbase + (size_t)(jc + t * 16 + l15) * QKW;
            bf16x8 kf0 = *(const bf16x8*)(kr + quad * 8);
            bf16x8 kf1 = *(const bf16x8*)(kr + 32 + quad * 8);
            f32x4 s4;
            #pragma unroll
            for (int r = 0; r < 4; ++r) s4[r] = 0.f;
            s4 = __builtin_amdgcn_mfma_f32_16x16x32_bf16(kf0, qf0, s4, 0, 0, 0);
            s4 = __builtin_amdgcn_mfma_f32_16x16x32_bf16(kf1, qf1, s4, 0, 0, 0);
            #pragma unroll
            for (int r = 0; r < 4; ++r) {
                const int gj = jc + t * 16 + quad * 4 + r;
                float mm = 0.f;
                if (anym) mm = mrow[gj];
                const int dist = gi > gj ? gi - gj : gj - gi;
                const float p = (dist > wsz) ? 0.f : __expf(fmaf(s4[r], SCALE, mm));
                lsum += p;
            }
        }
    }
    lsum += __shfl_xor(lsum, 16);
    lsum += __shfl_xor(lsum, 32);
    const float invl = 1.0f / lsum;
    const float sc   = invl * INV12;

    // ---- pass B: recompute, mean-atomics, PV ----
    f32x4 oacc[4];
    #pragma unroll
    for (int t = 0; t < 4; ++t)
        #pragma unroll
        for (int r = 0; r < 4; ++r) oacc[t][r] = 0.f;

    ushort_t* prow = &Pbuf[(w * 16 + l15) * 72];

    for (int ci = 0; ci < nch; ++ci) {
        const int jc = jbase + ci * 64;
        const int anym = flags[fbase + jt0 + ci];
        #pragma unroll
        for (int t = 0; t < 4; ++t) {
            const ushort_t* kr = kbase + (size_t)(jc + t * 16 + l15) * QKW;
            bf16x8 kf0 = *(const bf16x8*)(kr + quad * 8);
            bf16x8 kf1 = *(const bf16x8*)(kr + 32 + quad * 8);
            f32x4 s4;
            #pragma unroll
            for (int r = 0; r < 4; ++r) s4[r] = 0.f;
            s4 = __builtin_amdgcn_mfma_f32_16x16x32_bf16(kf0, qf0, s4, 0, 0, 0);
            s4 = __builtin_amdgcn_mfma_f32_16x16x32_bf16(kf1, qf1, s4, 0, 0, 0);
            float p[4];
            #pragma unroll
            for (int r = 0; r < 4; ++r) {
                const int gj = jc + t * 16 + quad * 4 + r;
                float mm = 0.f;
                if (anym) mm = mrow[gj];
                const int dist = gi > gj ? gi - gj : gj - gi;
                p[r] = (dist > wsz) ? 0.f : __expf(fmaf(s4[r], SCALE, mm));
                if (p[r] != 0.f)
                    atomicAdd(&accs[l15 * ACCW + (jc - jbase) + t * 16 + quad * 4 + r], p[r] * sc);
            }
            uint2 pk;
            pk.x = pack2bf(p[0], p[1]);
            pk.y = pack2bf(p[2], p[3]);
            *(uint2*)(prow + t * 16 + quad * 4) = pk;
        }
        // PV for this chunk: A = P (from slab), B = vt rows
        #pragma unroll
        for (int g = 0; g < 2; ++g) {
            bf16x8 pa = *(const bf16x8*)(prow + g * 32 + quad * 8);
            #pragma unroll
            for (int t2 = 0; t2 < 4; ++t2) {
                bf16x8 vf = *(const bf16x8*)(vbase + (size_t)(t2 * 16 + l15) * SEQ + jc + g * 32 + quad * 8);
                oacc[t2] = __builtin_amdgcn_mfma_f32_16x16x32_bf16(pa, vf, oacc[t2], 0, 0, 0);
            }
        }
    }

    // values epilogue: O lane layout = [row i = quad*4+r][col d = t2*16+l15]
    {
        float invr[4];
        #pragma unroll
        for (int r = 0; r < 4; ++r) invr[r] = __shfl(invl, quad * 4 + r, 16);
        #pragma unroll
        for (int t2 = 0; t2 < 4; ++t2) {
            #pragma unroll
            for (int r = 0; r < 4; ++r) {
                values[(size_t)(b * SEQ + iq0 + quad * 4 + r) * EDIM + h * 64 + t2 * 16 + l15] =
                    f2bf(oacc[t2][r] * invr[r]);
            }
        }
    }
    __syncthreads();

    // ---- write attn_mean: full rows, zeros outside window ----
    for (int f = tid; f < 16 * 512; f += 768) {
        const int i  = f >> 9;
        const int j  = (f & 511) * 4;
        const int o  = j - jbase;
        float4 v = {0.f, 0.f, 0.f, 0.f};
        if (o >= 0 && o < span) {
            v.x = accs[i * ACCW + o + 0];
            v.y = accs[i * ACCW + o + 1];
            v.z = accs[i * ACCW + o + 2];
            v.w = accs[i * ACCW + o + 3];
        }
        *(float4*)(attn_out + ((size_t)b * SEQ + iq0 + i) * SEQ + j) = v;
    }
}

extern "C" void kernel_launch(void* const* d_in, const int* in_sizes, int n_in,
                              void* d_out, int out_size, void* d_ws, size_t ws_size,
                              hipStream_t stream) {
    const float* x      = (const float*)d_in[0];
    const int*   pad    = (const int*)d_in[1];
    const float* mmask  = (const float*)d_in[2];
    const float* qkv_w  = (const float*)d_in[3];
    const float* qkv_b  = (const float*)d_in[4];
    const float* o_w    = (const float*)d_in[5];
    const float* o_b    = (const float*)d_in[6];

    float* out_o    = (float*)d_out;
    float* out_attn = out_o + (size_t)NB * SEQ * EDIM;

    ushort_t* qk     = (ushort_t*)d_ws;                       // NB*SEQ*1536
    ushort_t* vt     = qk + (size_t)NB * SEQ * QKW;           // NB*NH*64*SEQ
    ushort_t* xb     = vt + (size_t)NB * NH * 64 * SEQ;       // x bf16
    ushort_t* values = xb;                                    // alias (after GEMM1)
    ushort_t* wqkvb  = xb + (size_t)NB * SEQ * DIN;
    ushort_t* wob    = wqkvb + (size_t)QKVN * DIN;
    int*      wszp   = (int*)(wob + (size_t)EDIM * EDIM);
    int*      flags  = wszp + 4;

    hipMemsetAsync(flags, 0, (size_t)NB * 128 * 32 * sizeof(int), stream);

    wsz_kernel<<<NB, 256, 0, stream>>>(pad, wszp);
    flag_kernel<<<dim3(8, 128, NB), 256, 0, stream>>>(mmask, wszp, flags);

    const int nx = NB * SEQ * DIN / 4, nw1 = QKVN * DIN / 4, nw2 = EDIM * EDIM / 4;
    cvt3_kernel<<<(nx + nw1 + nw2 + 255) / 256, 256, 0, stream>>>(
        x, nx, qkv_w, nw1, o_w, nw2, xb, wqkvb, wob);

    mfma_gemm128<1><<<dim3(QKVN / 128, (NB * SEQ) / 128), 256, 0, stream>>>(
        xb, wqkvb, qkv_b, nullptr, qk, vt, QKVN, DIN);

    attn_kernel<<<512, 768, 0, stream>>>(
        qk, vt, mmask, wszp, flags, values, out_attn);

    mfma_gemm128<0><<<dim3(EDIM / 128, (NB * SEQ) / 128), 256, 0, stream>>>(
        values, wob, o_b, out_o, nullptr, nullptr, EDIM, EDIM);
}

// Round 10
// 328.918 us; speedup vs baseline: 1.5286x; 1.5286x over previous
//
#include <hip/hip_runtime.h>

#define SEQ 2048
#define NB 4
#define DIN 768
#define EDIM 768
#define NH 12
#define QKVN 2304
#define SCALE 0.125f
#define PADV -1e9f
#define INV12 (0.0833333333f)
#define PSW 520   // Ps row stride in elems

typedef unsigned short ushort_t;
typedef __attribute__((ext_vector_type(8))) short bf16x8;
typedef __attribute__((ext_vector_type(4))) float f32x4;

__device__ __forceinline__ float bf2f(ushort_t u) {
    union { unsigned int i; float f; } v; v.i = ((unsigned int)u) << 16; return v.f;
}
__device__ __forceinline__ ushort_t f2bf(float f) {
    union { float f; unsigned int i; } v; v.f = f;
    unsigned int r = (v.i + 0x7fffu + ((v.i >> 16) & 1u)) >> 16;
    return (ushort_t)r;
}
__device__ __forceinline__ void gl_lds16(const ushort_t* g, ushort_t* l) {
    __builtin_amdgcn_global_load_lds(
        (const __attribute__((address_space(1))) unsigned int*)(g),
        (__attribute__((address_space(3))) unsigned int*)(l),
        16, 0, 0);
}

// ---------------- fp32 -> bf16 conversion, 3 regions in one launch ----------------
__global__ void cvt3_kernel(const float* __restrict__ s0, int n0,
                            const float* __restrict__ s1, int n1,
                            const float* __restrict__ s2, int n2,
                            ushort_t* __restrict__ d0, ushort_t* __restrict__ d1,
                            ushort_t* __restrict__ d2) {
    int i = blockIdx.x * blockDim.x + threadIdx.x;
    const float* src; ushort_t* dst; int off;
    if (i < n0)               { src = s0; dst = d0; off = i; }
    else if (i < n0 + n1)     { src = s1; dst = d1; off = i - n0; }
    else if (i < n0 + n1 + n2){ src = s2; dst = d2; off = i - n0 - n1; }
    else return;
    float4 f = ((const float4*)src)[off];
    ushort4 u;
    u.x = f2bf(f.x); u.y = f2bf(f.y); u.z = f2bf(f.z); u.w = f2bf(f.w);
    ((ushort4*)dst)[off] = u;
}

// ---------------- 128x128 bf16 MFMA GEMM ----------------
// MODE 0: fp32 out. MODE 1: bf16 out split into qkh[b][h][tok][128] (Q|K) and
// vt[b][h][d][tok] (transposed V).
template<int MODE>
__global__ __launch_bounds__(256) void mfma_gemm128(
    const ushort_t* __restrict__ A, const ushort_t* __restrict__ Bw,
    const float* __restrict__ bias, float* __restrict__ outf,
    ushort_t* __restrict__ qkh, ushort_t* __restrict__ vt, int N, int K)
{
    __shared__ __align__(16) ushort_t Al[128 * 64];
    __shared__ __align__(16) ushort_t Bl[128 * 64];
    const int tid  = threadIdx.x;
    const int w    = tid >> 6;
    const int l    = tid & 63;
    const int quad = l >> 4;
    const int lr   = l & 15;
    const int mw   = (w >> 1) * 64;
    const int nw   = (w & 1) * 64;
    const int bm   = blockIdx.y * 128;
    const int bn   = blockIdx.x * 128;
    const int srow = l >> 3;
    const int sg   = (l & 7) ^ srow;

    f32x4 acc[4][4];
    #pragma unroll
    for (int i = 0; i < 4; ++i)
        #pragma unroll
        for (int j = 0; j < 4; ++j)
            #pragma unroll
            for (int r = 0; r < 4; ++r) acc[i][j][r] = 0.f;

    const ushort_t* ga = A  + (size_t)(bm + w * 32 + srow) * K + sg * 8;
    const ushort_t* gb = Bw + (size_t)(bn + w * 32 + srow) * K + sg * 8;
    ushort_t* la = &Al[(w * 32) * 64];
    ushort_t* lb = &Bl[(w * 32) * 64];

    for (int k0 = 0; k0 < K; k0 += 64) {
        __syncthreads();
        #pragma unroll
        for (int i = 0; i < 4; ++i)
            gl_lds16(ga + (size_t)(i * 8) * K + k0, la + i * 8 * 64);
        #pragma unroll
        for (int i = 0; i < 4; ++i)
            gl_lds16(gb + (size_t)(i * 8) * K + k0, lb + i * 8 * 64);
        __syncthreads();
        #pragma unroll
        for (int s = 0; s < 2; ++s) {
            bf16x8 af[4], bf[4];
            #pragma unroll
            for (int t = 0; t < 4; ++t)
                af[t] = *(const bf16x8*)&Al[(mw + t * 16 + lr) * 64 + (((4 * s + quad) ^ (lr & 7)) * 8)];
            #pragma unroll
            for (int t = 0; t < 4; ++t)
                bf[t] = *(const bf16x8*)&Bl[(nw + t * 16 + lr) * 64 + (((4 * s + quad) ^ (lr & 7)) * 8)];
            #pragma unroll
            for (int mt = 0; mt < 4; ++mt)
                #pragma unroll
                for (int nt = 0; nt < 4; ++nt)
                    acc[mt][nt] = __builtin_amdgcn_mfma_f32_16x16x32_bf16(af[mt], bf[nt], acc[mt][nt], 0, 0, 0);
        }
    }

    #pragma unroll
    for (int nt = 0; nt < 4; ++nt) {
        const int gn = bn + nw + nt * 16 + lr;
        const float bv = bias[gn];
        const int hh  = gn / 192;
        const int rem = gn - hh * 192;
        #pragma unroll
        for (int mt = 0; mt < 4; ++mt) {
            const int gm0 = bm + mw + mt * 16 + quad * 4;
            if (MODE == 0) {
                #pragma unroll
                for (int r = 0; r < 4; ++r)
                    outf[(size_t)(gm0 + r) * N + gn] = acc[mt][nt][r] + bv;
            } else if (rem < 128) {
                const int bb  = gm0 >> 11;
                const int tok = gm0 & (SEQ - 1);
                #pragma unroll
                for (int r = 0; r < 4; ++r)
                    qkh[((size_t)(bb * NH + hh) * SEQ + tok + r) * 128 + rem] =
                        f2bf(acc[mt][nt][r] + bv);
            } else {
                const int bb  = gm0 >> 11;
                const int tok = gm0 & (SEQ - 1);
                ushort4 st;
                st.x = f2bf(acc[mt][nt][0] + bv);
                st.y = f2bf(acc[mt][nt][1] + bv);
                st.z = f2bf(acc[mt][nt][2] + bv);
                st.w = f2bf(acc[mt][nt][3] + bv);
                *(ushort4*)&vt[((size_t)(bb * NH + hh) * 64 + (rem - 128)) * SEQ + tok] = st;
            }
        }
    }
}

// ---------------- fused windowed attention (round-6 structure + inline wsz/flags) ----
// Grid 512 (XCD-swizzled), 512 thr = 8 waves; waves 0-3 -> even head, 4-7 -> odd.
__global__ __launch_bounds__(512) void attn_kernel(
    const ushort_t* __restrict__ qkh,   // [NB*NH*SEQ][128] bf16 (Q|K per head)
    const ushort_t* __restrict__ vt,    // [NB*NH*64][SEQ] bf16 (V transposed)
    const float* __restrict__ mmask,    // [NB][SEQ][SEQ]
    const int* __restrict__ pad,        // [NB][SEQ]
    ushort_t* __restrict__ values,      // [NB*SEQ][768] bf16
    float* __restrict__ attn_out)       // [NB][SEQ][SEQ]
{
    __shared__ __align__(16) ushort_t Ps[2][16 * PSW];  // 33.3 KB
    __shared__ float lsump[2][4][16];
    __shared__ int s_cnt[8];
    __shared__ int s_flags[8];
    const int tid  = threadIdx.x;
    const int w    = tid >> 6;       // 0..7
    const int hg   = w >> 2;         // head-group 0/1
    const int ww   = w & 3;          // wave within head
    const int lane = tid & 63;
    const int quad = lane >> 4;
    const int lr   = lane & 15;

    const int lin  = blockIdx.x;
    const int s    = lin & 1;
    const int b    = (lin >> 1) & 3;
    const int i16  = (lin >> 3) + 64 * s;
    const int iq0  = i16 * 16;

    // ---- inline window size (popcount of valid tokens) ----
    {
        int4 pv = *(const int4*)&pad[b * SEQ + tid * 4];
        int c = (pv.x == 0) + (pv.y == 0) + (pv.z == 0) + (pv.w == 0);
        #pragma unroll
        for (int o = 32; o; o >>= 1) c += __shfl_down(c, o, 64);
        if (lane == 0) s_cnt[w] = c;
        if (tid < 8) s_flags[tid] = 0;
    }
    __syncthreads();
    int len = 0;
    #pragma unroll
    for (int k = 0; k < 8; ++k) len += s_cnt[k];
    if (len > 2048) len = 2048;
    int wsz = (int)ceilf((float)len * 10.0f / 100.0f);
    if (wsz < 2) wsz = 2;

    const int jlo  = max(0, iq0 - wsz);
    const int jhi  = min(SEQ - 1, iq0 + 15 + wsz);
    const int jt0  = jlo >> 6;
    const int nch  = (jhi >> 6) - jt0 + 1;   // <= 8
    const int jbase = jt0 << 6;
    const int span  = nch << 6;              // <= 512

    // ---- inline mmask nonzero-tile flags (coalesced scan of own window) ----
    {
        const float* tp = mmask + ((size_t)b * SEQ + iq0) * SEQ + jbase;
        const int e = tid * 2, row = e >> 6, col = e & 63;
        for (int ci = 0; ci < nch; ++ci) {
            float2 v = *(const float2*)&tp[(size_t)row * SEQ + ci * 64 + col];
            if (__any(v.x != 0.f || v.y != 0.f)) {
                if (lane == 0) atomicOr(&s_flags[ci], 1);
            }
        }
    }

    // mean-accum ownership: row = tid&15, col-group = tid>>4 (16 cols each)
    const int arow = tid & 15;
    const int acg  = tid >> 4;
    float acc[16];
    #pragma unroll
    for (int k = 0; k < 16; ++k) acc[k] = 0.f;
    __syncthreads();   // s_flags ready

    const ushort_t* vhead = vt + (size_t)b * NH * 64 * SEQ;

    for (int hp = 0; hp < NH / 2; ++hp) {
        const int h = hp * 2 + hg;
        const ushort_t* hbase = qkh + (size_t)(b * NH + h) * SEQ * 128;
        const ushort_t* qbase = hbase + (size_t)(iq0 + lr) * 128;
        const bf16x8 qf0 = *(const bf16x8*)(qbase + quad * 8);
        const bf16x8 qf1 = *(const bf16x8*)(qbase + 32 + quad * 8);

        // ---- QK + exp for this wave's chunks (ci = ww, ww+4) ----
        float ls[4] = {0.f, 0.f, 0.f, 0.f};
        #pragma unroll
        for (int cc = 0; cc < 2; ++cc) {
            const int ci = ww + cc * 4;
            if (ci < nch) {
                const int jc = jbase + ci * 64;
                f32x4 s4[4];
                #pragma unroll
                for (int t = 0; t < 4; ++t) {
                    const ushort_t* kr = hbase + (size_t)(jc + t * 16 + lr) * 128 + 64;
                    bf16x8 kf0 = *(const bf16x8*)(kr + quad * 8);
                    bf16x8 kf1 = *(const bf16x8*)(kr + 32 + quad * 8);
                    #pragma unroll
                    for (int r = 0; r < 4; ++r) s4[t][r] = 0.f;
                    s4[t] = __builtin_amdgcn_mfma_f32_16x16x32_bf16(qf0, kf0, s4[t], 0, 0, 0);
                    s4[t] = __builtin_amdgcn_mfma_f32_16x16x32_bf16(qf1, kf1, s4[t], 0, 0, 0);
                }
                const int anym = s_flags[ci];
                #pragma unroll
                for (int t = 0; t < 4; ++t) {
                    const int gj = jc + t * 16 + lr;
                    #pragma unroll
                    for (int r = 0; r < 4; ++r) {
                        const int gi = iq0 + quad * 4 + r;
                        float mm = 0.f;
                        if (anym) mm = mmask[((size_t)b * SEQ + gi) * SEQ + gj];
                        const int dist = gi > gj ? gi - gj : gj - gi;
                        const float p = (dist > wsz) ? 0.f : __expf(fmaf(s4[t][r], SCALE, mm));
                        ls[r] += p;
                        Ps[hg][(quad * 4 + r) * PSW + (ci * 64 + t * 16 + lr)] = f2bf(p);
                    }
                }
            }
        }
        #pragma unroll
        for (int r = 0; r < 4; ++r) {
            #pragma unroll
            for (int m = 8; m; m >>= 1) ls[r] += __shfl_xor(ls[r], m, 16);
        }
        if (lr == 0) {
            #pragma unroll
            for (int r = 0; r < 4; ++r) lsump[hg][ww][quad * 4 + r] = ls[r];
        }
        __syncthreads();

        // ---- head-mean accumulation into registers (both heads of the pair) ----
        if (acg * 16 < span) {
            const float l0 = lsump[0][0][arow] + lsump[0][1][arow] + lsump[0][2][arow] + lsump[0][3][arow];
            const float l1 = lsump[1][0][arow] + lsump[1][1][arow] + lsump[1][2][arow] + lsump[1][3][arow];
            const float sc0 = INV12 / l0;
            const float sc1 = INV12 / l1;
            const ushort_t* p0 = &Ps[0][arow * PSW + acg * 16];
            const ushort_t* p1 = &Ps[1][arow * PSW + acg * 16];
            #pragma unroll
            for (int k = 0; k < 4; ++k) {
                ushort4 u0 = *(const ushort4*)(p0 + k * 4);
                ushort4 u1 = *(const ushort4*)(p1 + k * 4);
                acc[k * 4 + 0] = fmaf(bf2f(u0.x), sc0, fmaf(bf2f(u1.x), sc1, acc[k * 4 + 0]));
                acc[k * 4 + 1] = fmaf(bf2f(u0.y), sc0, fmaf(bf2f(u1.y), sc1, acc[k * 4 + 1]));
                acc[k * 4 + 2] = fmaf(bf2f(u0.z), sc0, fmaf(bf2f(u1.z), sc1, acc[k * 4 + 2]));
                acc[k * 4 + 3] = fmaf(bf2f(u0.w), sc0, fmaf(bf2f(u1.w), sc1, acc[k * 4 + 3]));
            }
        }

        // ---- PV: wave computes head h, d-slice [ww*16, ww*16+16) ----
        {
            f32x4 oacc;
            #pragma unroll
            for (int r = 0; r < 4; ++r) oacc[r] = 0.f;
            const ushort_t* vrow = vhead + (size_t)(h * 64 + ww * 16 + lr) * SEQ + jbase;
            for (int ci = 0; ci < nch; ++ci) {
                const int tok0 = ci * 64;
                #pragma unroll
                for (int s2 = 0; s2 < 2; ++s2) {
                    bf16x8 pa = *(const bf16x8*)&Ps[hg][lr * PSW + tok0 + s2 * 32 + quad * 8];
                    bf16x8 vf = *(const bf16x8*)(vrow + tok0 + s2 * 32 + quad * 8);
                    oacc = __builtin_amdgcn_mfma_f32_16x16x32_bf16(pa, vf, oacc, 0, 0, 0);
                }
            }
            float lr4[4];
            #pragma unroll
            for (int r = 0; r < 4; ++r)
                lr4[r] = lsump[hg][0][quad * 4 + r] + lsump[hg][1][quad * 4 + r] +
                         lsump[hg][2][quad * 4 + r] + lsump[hg][3][quad * 4 + r];
            #pragma unroll
            for (int r = 0; r < 4; ++r) {
                const int row = iq0 + quad * 4 + r;
                values[(size_t)(b * SEQ + row) * EDIM + h * 64 + ww * 16 + lr] =
                    f2bf(oacc[r] / lr4[r]);
            }
        }
        __syncthreads();   // Ps/lsump reuse next head pair
    }

    // ---- write attn_mean ----
    if (acg * 16 < span) {
        float* dst = attn_out + ((size_t)b * SEQ + iq0 + arow) * SEQ + jbase + acg * 16;
        #pragma unroll
        for (int k = 0; k < 4; ++k) {
            float4 v = { acc[k * 4 + 0], acc[k * 4 + 1], acc[k * 4 + 2], acc[k * 4 + 3] };
            *(float4*)(dst + k * 4) = v;
        }
    }
    {
        const int c4lo = jbase >> 2;
        const int c4hi = (jbase + span) >> 2;
        const float4 z = {0.f, 0.f, 0.f, 0.f};
        for (int f = tid; f < 16 * 512; f += 512) {
            const int i  = f >> 9;
            const int c4 = f & 511;
            if (c4 < c4lo || c4 >= c4hi)
                *(float4*)(attn_out + ((size_t)b * SEQ + iq0 + i) * SEQ + c4 * 4) = z;
        }
    }
}

extern "C" void kernel_launch(void* const* d_in, const int* in_sizes, int n_in,
                              void* d_out, int out_size, void* d_ws, size_t ws_size,
                              hipStream_t stream) {
    const float* x      = (const float*)d_in[0];
    const int*   pad    = (const int*)d_in[1];
    const float* mmask  = (const float*)d_in[2];
    const float* qkv_w  = (const float*)d_in[3];
    const float* qkv_b  = (const float*)d_in[4];
    const float* o_w    = (const float*)d_in[5];
    const float* o_b    = (const float*)d_in[6];

    float* out_o    = (float*)d_out;
    float* out_attn = out_o + (size_t)NB * SEQ * EDIM;

    ushort_t* qkh    = (ushort_t*)d_ws;                       // NB*NH*SEQ*128  25.2 MB
    ushort_t* vt     = qkh + (size_t)NB * NH * SEQ * 128;     // NB*NH*64*SEQ   12.6 MB
    ushort_t* xb     = vt + (size_t)NB * NH * 64 * SEQ;       // x bf16         12.6 MB
    ushort_t* values = xb;                                    // alias (after GEMM1)
    ushort_t* wqkvb  = xb + (size_t)NB * SEQ * DIN;           // qkv_w bf16      3.5 MB
    ushort_t* wob    = wqkvb + (size_t)QKVN * DIN;            // o_w bf16        1.2 MB

    const int nx = NB * SEQ * DIN / 4, nw1 = QKVN * DIN / 4, nw2 = EDIM * EDIM / 4;
    cvt3_kernel<<<(nx + nw1 + nw2 + 255) / 256, 256, 0, stream>>>(
        x, nx, qkv_w, nw1, o_w, nw2, xb, wqkvb, wob);

    mfma_gemm128<1><<<dim3(QKVN / 128, (NB * SEQ) / 128), 256, 0, stream>>>(
        xb, wqkvb, qkv_b, nullptr, qkh, vt, QKVN, DIN);

    attn_kernel<<<512, 512, 0, stream>>>(
        qkh, vt, mmask, pad, values, out_attn);

    mfma_gemm128<0><<<dim3(EDIM / 128, (NB * SEQ) / 128), 256, 0, stream>>>(
        values, wob, o_b, out_o, nullptr, nullptr, EDIM, EDIM);
}